// Round 3
// baseline (215.421 us; speedup 1.0000x reference)
//
#include <hip/hip_runtime.h>

#define NN 64000
#define NG 512
#define NPG 125
#define DIM 128
#define NC 10
#define SHID 69
#define NF 16
#define PHID 8

// output float offsets (concatenated tuple, row-major)
#define OFF_PRED1 0
#define OFF_PRED2 1024
#define OFF_IND   2048
#define OFF_S     2560
#define OFF_E     642560
#define OFF_Q     1297920

// ---------------- threefry2x32 (JAX-exact, key = (0, 42)) ----------------
__device__ __forceinline__ unsigned rotl32(unsigned x, int r) {
    return (x << r) | (x >> (32 - r));
}

__device__ __forceinline__ void threefry_0_42(unsigned x0, unsigned x1,
                                              unsigned& o0, unsigned& o1) {
    const unsigned k0 = 0u, k1 = 42u;
    const unsigned k2 = k0 ^ k1 ^ 0x1BD11BDAu;
    unsigned ks[3] = {k0, k1, k2};
    const int R0[4] = {13, 15, 26, 6};
    const int R1[4] = {17, 29, 16, 24};
    x0 += k0; x1 += k1;
    #pragma unroll
    for (int i = 0; i < 5; i++) {
        const int* R = (i & 1) ? R1 : R0;
        #pragma unroll
        for (int r = 0; r < 4; r++) {
            x0 += x1;
            x1 = rotl32(x1, R[r]);
            x1 ^= x0;
        }
        x0 += ks[(i + 1) % 3];
        x1 += ks[(i + 2) % 3] + (unsigned)(i + 1);
    }
    o0 = x0; o1 = x1;
}

// jax_threefry_partitionable=True (default in modern JAX):
// element i -> counter words (hi, lo) = (0, i) via iota_2x32_shape;
// bits1, bits2 = threefry2x32(key, hi, lo);
// for bit_width==32: bits = bits1 ^ bits2   (XOR fold, prng.py)
__device__ __forceinline__ unsigned random_bits_partitionable(unsigned i) {
    unsigned o0, o1;
    threefry_0_42(0u, i, o0, o1);
    return o0 ^ o1;
}

__device__ __forceinline__ float gumbel_from_bits(unsigned bits) {
    float f = __uint_as_float((bits >> 9) | 0x3f800000u) - 1.0f;  // [0,1)
    if (f <= 0.0f) f = 1.1754943508222875e-38f;                   // minval=tiny
    return -logf(-logf(f));
}

// ---------------- K1: per-node MLP 128->69(relu)->10 + softmax ----------------
__global__ __launch_bounds__(256) void k_node_mlp(
    const float* __restrict__ H, const float* __restrict__ w1,
    const float* __restrict__ b1, const float* __restrict__ w2,
    const float* __restrict__ b2, float* __restrict__ S) {
    int n = blockIdx.x * 256 + threadIdx.x;  // exact: 64000 = 250*256
    const float4* H4 = (const float4*)H + (size_t)n * 32;

    float t[SHID];
    #pragma unroll
    for (int j = 0; j < SHID; j++) t[j] = b1[j];

    #pragma unroll 2
    for (int k4 = 0; k4 < 32; k4++) {
        float4 h4 = H4[k4];
        float hs[4] = {h4.x, h4.y, h4.z, h4.w};
        #pragma unroll
        for (int kk = 0; kk < 4; kk++) {
            float hk = hs[kk];
            const float* wrow = w1 + (k4 * 4 + kk) * SHID;  // wave-uniform -> s_load
            #pragma unroll
            for (int j = 0; j < SHID; j++) t[j] = fmaf(hk, wrow[j], t[j]);
        }
    }

    float lg[NC];
    #pragma unroll
    for (int c = 0; c < NC; c++) lg[c] = b2[c];
    #pragma unroll
    for (int j = 0; j < SHID; j++) {
        float tr = fmaxf(t[j], 0.0f);
        const float* w2r = w2 + j * NC;  // wave-uniform
        #pragma unroll
        for (int c = 0; c < NC; c++) lg[c] = fmaf(tr, w2r[c], lg[c]);
    }

    float m = lg[0];
    #pragma unroll
    for (int c = 1; c < NC; c++) m = fmaxf(m, lg[c]);
    float e[NC], s = 0.0f;
    #pragma unroll
    for (int c = 0; c < NC; c++) { e[c] = expf(lg[c] - m); s += e[c]; }
    float inv = 1.0f / s;
    float* Sp = S + (size_t)n * NC;
    #pragma unroll
    for (int c = 0; c < NC; c++) Sp[c] = e[c] * inv;
}

// ---------------- K2: E[b,c,d] = sum_{n in graph b} S[n,c] * H[n,d] ----------------
__global__ __launch_bounds__(256) void k_E(const float* __restrict__ H,
                                           const float* __restrict__ S,
                                           float* __restrict__ E) {
    __shared__ float Hs[32 * DIM];
    __shared__ float Ss[32 * NC];
    int b = blockIdx.x;
    int tid = threadIdx.x;
    int d = tid & 127;
    int ch = tid >> 7;  // 0 or 1 -> clusters [0..4] or [5..9]
    float acc[5] = {0.f, 0.f, 0.f, 0.f, 0.f};
    int base = b * NPG;

    for (int nb = 0; nb < NPG; nb += 32) {
        int cnt = min(32, NPG - nb);
        const float4* H4 = (const float4*)H + (size_t)(base + nb) * 32;
        for (int i = tid; i < cnt * 32; i += 256) ((float4*)Hs)[i] = H4[i];
        const float* Sg = S + (size_t)(base + nb) * NC;
        for (int i = tid; i < cnt * NC; i += 256) Ss[i] = Sg[i];
        __syncthreads();
        for (int n = 0; n < cnt; n++) {
            float hv = Hs[n * DIM + d];               // stride-1 across lanes: conflict-free
            const float* sr = Ss + n * NC + ch * 5;   // wave-uniform: broadcast
            #pragma unroll
            for (int i = 0; i < 5; i++) acc[i] = fmaf(sr[i], hv, acc[i]);
        }
        __syncthreads();
    }
    float* Eo = E + (size_t)b * 1280 + ch * 5 * DIM + d;
    #pragma unroll
    for (int i = 0; i < 5; i++) Eo[i * DIM] = acc[i];
}

// ---------------- K0: correlation = softmax(ci,axis=0)*softmax(cr,axis=1) [2,16] ----------------
__global__ void k_corr(const float* __restrict__ ci, const float* __restrict__ cr,
                       float* __restrict__ corr) {
    int f = threadIdx.x;
    if (f < NF) {
        float a = ci[f], b = ci[NF + f];
        float m = fmaxf(a, b);
        float ea = expf(a - m), eb = expf(b - m), s = ea + eb;
        float i0 = ea / s, i1 = eb / s;
        float m0 = -1e30f, m1 = -1e30f;
        for (int j = 0; j < NF; j++) {
            m0 = fmaxf(m0, cr[j]);
            m1 = fmaxf(m1, cr[NF + j]);
        }
        float r0 = 0.f, r1 = 0.f;
        for (int j = 0; j < NF; j++) {
            r0 += expf(cr[j] - m0);
            r1 += expf(cr[NF + j] - m1);
        }
        float t0 = expf(cr[f] - m0) / r0;
        float t1 = expf(cr[NF + f] - m1) / r1;
        corr[f] = i0 * t0;
        corr[NF + f] = i1 * t1;
    }
}

// ---------------- K3: pred1 + softmax + threefry-gumbel sample + ind ----------------
__global__ __launch_bounds__(64) void k_pred1(
    const float* __restrict__ E, const float* __restrict__ wf,
    const float* __restrict__ bf, const int* __restrict__ targets,
    float* __restrict__ pred1, float* __restrict__ ind,
    int* __restrict__ sample_ws) {
    int b = blockIdx.x, l = threadIdx.x;
    const float* Er = E + (size_t)b * 1280;
    const float2* wf2 = (const float2*)wf;
    float a0 = 0.f, a1 = 0.f;
    #pragma unroll
    for (int i = 0; i < 20; i++) {
        int idx = i * 64 + l;
        float e = Er[idx];
        float2 w = wf2[idx];
        a0 = fmaf(e, w.x, a0);
        a1 = fmaf(e, w.y, a1);
    }
    #pragma unroll
    for (int off = 32; off > 0; off >>= 1) {
        a0 += __shfl_down(a0, off);
        a1 += __shfl_down(a1, off);
    }
    if (l == 0) {
        float y0 = a0 + bf[0], y1 = a1 + bf[1];
        pred1[b * 2] = y0;
        pred1[b * 2 + 1] = y1;
        float m = fmaxf(y0, y1);
        float e0 = expf(y0 - m), e1 = expf(y1 - m), s = e0 + e1;
        float p0 = e0 / s, p1 = e1 / s;
        float g0 = gumbel_from_bits(random_bits_partitionable(2 * b));
        float g1 = gumbel_from_bits(random_bits_partitionable(2 * b + 1));
        float l0 = logf(p0 + 1e-12f) + g0;
        float l1 = logf(p1 + 1e-12f) + g1;
        int samp = (l1 > l0) ? 1 : 0;  // argmax, first index wins ties
        ind[b] = (samp == targets[b]) ? 1.0f : 0.0f;
        sample_ws[b] = samp;
    }
}

// ---------------- K4: Q = softmax(MLP 128->8(relu)->16) + feature_mask ----------------
__global__ __launch_bounds__(256) void k_Q(
    const float* __restrict__ E, const float* __restrict__ p1,
    const float* __restrict__ pb1, const float* __restrict__ p2,
    const float* __restrict__ pb2, const float* __restrict__ corr,
    const int* __restrict__ sample_ws, float* __restrict__ Q,
    float* __restrict__ fm) {
    int t = blockIdx.x * 256 + threadIdx.x;  // < 5120 = (b,c) pairs
    const float4* Er4 = (const float4*)(E + (size_t)t * DIM);

    float u[PHID];
    #pragma unroll
    for (int j = 0; j < PHID; j++) u[j] = pb1[j];
    #pragma unroll 2
    for (int k4 = 0; k4 < 32; k4++) {
        float4 e4 = Er4[k4];
        float es[4] = {e4.x, e4.y, e4.z, e4.w};
        #pragma unroll
        for (int kk = 0; kk < 4; kk++) {
            const float* pr = p1 + (k4 * 4 + kk) * PHID;  // wave-uniform
            #pragma unroll
            for (int j = 0; j < PHID; j++) u[j] = fmaf(es[kk], pr[j], u[j]);
        }
    }
    float v[NF];
    #pragma unroll
    for (int f = 0; f < NF; f++) v[f] = pb2[f];
    #pragma unroll
    for (int j = 0; j < PHID; j++) {
        float uj = fmaxf(u[j], 0.0f);
        const float* pr = p2 + j * NF;  // wave-uniform
        #pragma unroll
        for (int f = 0; f < NF; f++) v[f] = fmaf(uj, pr[f], v[f]);
    }
    float m = v[0];
    #pragma unroll
    for (int f = 1; f < NF; f++) m = fmaxf(m, v[f]);
    float s = 0.f, q[NF];
    #pragma unroll
    for (int f = 0; f < NF; f++) { q[f] = expf(v[f] - m); s += q[f]; }
    float inv = 1.0f / s;
    #pragma unroll
    for (int f = 0; f < NF; f++) q[f] *= inv;
    float* Qo = Q + (size_t)t * NF;
    #pragma unroll
    for (int f4 = 0; f4 < 4; f4++)
        ((float4*)Qo)[f4] = make_float4(q[f4 * 4], q[f4 * 4 + 1], q[f4 * 4 + 2], q[f4 * 4 + 3]);

    int b = t / NC;
    int samp = sample_ws[b];
    const float* cm = corr + samp * NF;
    float fmv = 0.f;
    #pragma unroll
    for (int f = 0; f < NF; f++) fmv = fmaf(q[f], cm[f], fmv);
    fm[t] = fmv;  // fm[b*10+c]
}

// ---------------- K5: pred2 = (fm[:,:,None]*E).reshape(B,-1) @ wf + bf ----------------
__global__ __launch_bounds__(64) void k_pred2(
    const float* __restrict__ E, const float* __restrict__ wf,
    const float* __restrict__ bf, const float* __restrict__ fm,
    float* __restrict__ pred2) {
    int b = blockIdx.x, l = threadIdx.x;
    const float* Er = E + (size_t)b * 1280;
    const float* fmr = fm + b * NC;
    const float2* wf2 = (const float2*)wf;
    float a0 = 0.f, a1 = 0.f;
    #pragma unroll
    for (int i = 0; i < 20; i++) {
        int idx = i * 64 + l;
        float e = Er[idx] * fmr[idx >> 7];
        float2 w = wf2[idx];
        a0 = fmaf(e, w.x, a0);
        a1 = fmaf(e, w.y, a1);
    }
    #pragma unroll
    for (int off = 32; off > 0; off >>= 1) {
        a0 += __shfl_down(a0, off);
        a1 += __shfl_down(a1, off);
    }
    if (l == 0) {
        pred2[b * 2] = a0 + bf[0];
        pred2[b * 2 + 1] = a1 + bf[1];
    }
}

extern "C" void kernel_launch(void* const* d_in, const int* in_sizes, int n_in,
                              void* d_out, int out_size, void* d_ws, size_t ws_size,
                              hipStream_t stream) {
    const float* H       = (const float*)d_in[0];
    // d_in[1] = batch (implied by n/125, unused)
    const int*   targets = (const int*)d_in[2];
    const float* w1      = (const float*)d_in[3];
    const float* b1      = (const float*)d_in[4];
    const float* w2      = (const float*)d_in[5];
    const float* b2      = (const float*)d_in[6];
    const float* wf      = (const float*)d_in[7];
    const float* bf      = (const float*)d_in[8];
    const float* p1      = (const float*)d_in[9];
    const float* pb1     = (const float*)d_in[10];
    const float* p2      = (const float*)d_in[11];
    const float* pb2     = (const float*)d_in[12];
    const float* ci      = (const float*)d_in[13];
    const float* cr      = (const float*)d_in[14];

    float* out   = (float*)d_out;
    float* pred1 = out + OFF_PRED1;
    float* pred2 = out + OFF_PRED2;
    float* ind   = out + OFF_IND;
    float* S     = out + OFF_S;
    float* E     = out + OFF_E;
    float* Q     = out + OFF_Q;

    char*  ws     = (char*)d_ws;
    float* corr   = (float*)ws;               // 32 floats
    int*   sample = (int*)(ws + 128);         // 512 ints
    float* fm     = (float*)(ws + 128 + 2048);// 5120 floats

    k_node_mlp<<<NN / 256, 256, 0, stream>>>(H, w1, b1, w2, b2, S);
    k_E<<<NG, 256, 0, stream>>>(H, S, E);
    k_corr<<<1, 64, 0, stream>>>(ci, cr, corr);
    k_pred1<<<NG, 64, 0, stream>>>(E, wf, bf, targets, pred1, ind, sample);
    k_Q<<<5120 / 256, 256, 0, stream>>>(E, p1, pb1, p2, pb2, corr, sample, Q, fm);
    k_pred2<<<NG, 64, 0, stream>>>(E, wf, bf, fm, pred2);
}

// Round 4
// 179.617 us; speedup vs baseline: 1.1993x; 1.1993x over previous
//
#include <hip/hip_runtime.h>

#define NN 64000
#define NG 512
#define NPG 125
#define DIM 128
#define NC 10
#define SHID 69
#define NF 16
#define PHID 8

// output float offsets (concatenated tuple, row-major)
#define OFF_PRED1 0
#define OFF_PRED2 1024
#define OFF_IND   2048
#define OFF_S     2560
#define OFF_E     642560
#define OFF_Q     1297920

// ---------------- threefry2x32 (JAX-exact, key = (0, 42)) ----------------
__device__ __forceinline__ unsigned rotl32(unsigned x, int r) {
    return (x << r) | (x >> (32 - r));
}

__device__ __forceinline__ void threefry_0_42(unsigned x0, unsigned x1,
                                              unsigned& o0, unsigned& o1) {
    const unsigned k0 = 0u, k1 = 42u;
    const unsigned k2 = k0 ^ k1 ^ 0x1BD11BDAu;
    unsigned ks[3] = {k0, k1, k2};
    const int R0[4] = {13, 15, 26, 6};
    const int R1[4] = {17, 29, 16, 24};
    x0 += k0; x1 += k1;
    #pragma unroll
    for (int i = 0; i < 5; i++) {
        const int* R = (i & 1) ? R1 : R0;
        #pragma unroll
        for (int r = 0; r < 4; r++) {
            x0 += x1;
            x1 = rotl32(x1, R[r]);
            x1 ^= x0;
        }
        x0 += ks[(i + 1) % 3];
        x1 += ks[(i + 2) % 3] + (unsigned)(i + 1);
    }
    o0 = x0; o1 = x1;
}

// jax_threefry_partitionable: element i -> counter (0, i); bits = o0 ^ o1. (verified R2)
__device__ __forceinline__ unsigned random_bits_partitionable(unsigned i) {
    unsigned o0, o1;
    threefry_0_42(0u, i, o0, o1);
    return o0 ^ o1;
}

__device__ __forceinline__ float gumbel_from_bits(unsigned bits) {
    float f = __uint_as_float((bits >> 9) | 0x3f800000u) - 1.0f;  // [0,1)
    if (f <= 0.0f) f = 1.1754943508222875e-38f;                   // minval=tiny
    return -logf(-logf(f));
}

// ---------------- K1: per-node MLP 128->69(relu)->10 + softmax ----------------
// 64-thread blocks, launch_bounds(64,1): VGPR budget 512 -> t[69] stays in registers.
__global__ __launch_bounds__(64, 1) void k_node_mlp(
    const float* __restrict__ H, const float* __restrict__ w1,
    const float* __restrict__ b1, const float* __restrict__ w2,
    const float* __restrict__ b2, float* __restrict__ S) {
    int n = blockIdx.x * 64 + threadIdx.x;  // exact: 64000 = 1000*64
    const float4* H4 = (const float4*)H + (size_t)n * 32;

    float t[SHID];
    #pragma unroll
    for (int j = 0; j < SHID; j++) t[j] = b1[j];

    #pragma unroll 4
    for (int k4 = 0; k4 < 32; k4++) {
        float4 h4 = H4[k4];
        float hs[4] = {h4.x, h4.y, h4.z, h4.w};
        #pragma unroll
        for (int kk = 0; kk < 4; kk++) {
            float hk = hs[kk];
            const float* wrow = w1 + (k4 * 4 + kk) * SHID;  // wave-uniform -> s_load
            #pragma unroll
            for (int j = 0; j < SHID; j++) t[j] = fmaf(hk, wrow[j], t[j]);
        }
    }

    float lg[NC];
    #pragma unroll
    for (int c = 0; c < NC; c++) lg[c] = b2[c];
    #pragma unroll
    for (int j = 0; j < SHID; j++) {
        float tr = fmaxf(t[j], 0.0f);
        const float* w2r = w2 + j * NC;  // wave-uniform
        #pragma unroll
        for (int c = 0; c < NC; c++) lg[c] = fmaf(tr, w2r[c], lg[c]);
    }

    float m = lg[0];
    #pragma unroll
    for (int c = 1; c < NC; c++) m = fmaxf(m, lg[c]);
    float e[NC], s = 0.0f;
    #pragma unroll
    for (int c = 0; c < NC; c++) { e[c] = expf(lg[c] - m); s += e[c]; }
    float inv = 1.0f / s;
    float* Sp = S + (size_t)n * NC;
    #pragma unroll
    for (int c = 0; c < NC; c++) Sp[c] = e[c] * inv;
}

// ---------------- K2: E[g,c,d] = sum_n S[n,c]*H[n,d] — no LDS, no spill ----------------
// block = graph (128 threads = d). H coalesced stream; S row wave-uniform -> s_load.
__global__ __launch_bounds__(128, 1) void k_E(const float* __restrict__ H,
                                              const float* __restrict__ S,
                                              float* __restrict__ E) {
    int g = blockIdx.x;
    int d = threadIdx.x;
    const float* Hg = H + (size_t)g * NPG * DIM + d;
    const float* Sg = S + (size_t)g * NPG * NC;
    float acc[NC] = {0.f, 0.f, 0.f, 0.f, 0.f, 0.f, 0.f, 0.f, 0.f, 0.f};
    #pragma unroll 5
    for (int n = 0; n < NPG; n++) {
        float h = Hg[(size_t)n * DIM];
        const float* sr = Sg + n * NC;  // uniform address -> scalar loads
        #pragma unroll
        for (int c = 0; c < NC; c++) acc[c] = fmaf(sr[c], h, acc[c]);
    }
    float* Eo = E + (size_t)g * (NC * DIM) + d;
    #pragma unroll
    for (int c = 0; c < NC; c++) Eo[c * DIM] = acc[c];
}

// ---------------- K3: fused tail — corr + pred1 + sample + Q + fm + pred2 ----------------
// 512 blocks x 64 threads (1 wave). Block = graph.
__global__ __launch_bounds__(64, 1) void k_tail(
    const float* __restrict__ E, const float* __restrict__ wf,
    const float* __restrict__ bf, const int* __restrict__ targets,
    const float* __restrict__ p1, const float* __restrict__ pb1,
    const float* __restrict__ p2, const float* __restrict__ pb2,
    const float* __restrict__ ci, const float* __restrict__ cr,
    float* __restrict__ pred1, float* __restrict__ pred2,
    float* __restrict__ ind, float* __restrict__ Q) {
    __shared__ float fmbuf[NC];
    int g = blockIdx.x, l = threadIdx.x;
    const float* Er = E + (size_t)g * 1280;
    const float2* wf2 = (const float2*)wf;

    // ---- corr: lane l<32 computes corr[i=l>>4][f=l&15] ----
    float corr_lf = 0.f;
    {
        int i = l >> 4, f = l & 15;
        if (l < 32) {
            float a = ci[f], b = ci[NF + f];
            float mm = fmaxf(a, b);
            float ea = expf(a - mm), eb = expf(b - mm);
            float inter = expf(ci[i * NF + f] - mm) / (ea + eb);
            float mi = -1e30f;
            for (int j = 0; j < NF; j++) mi = fmaxf(mi, cr[i * NF + j]);
            float ri = 0.f;
            for (int j = 0; j < NF; j++) ri += expf(cr[i * NF + j] - mi);
            float intra = expf(cr[i * NF + f] - mi) / ri;
            corr_lf = inter * intra;
        }
    }

    // ---- phase 1: pred1 + softmax + gumbel sample + ind ----
    float a0 = 0.f, a1 = 0.f;
    #pragma unroll
    for (int i = 0; i < 20; i++) {
        int idx = i * 64 + l;
        float e = Er[idx];
        float2 w = wf2[idx];
        a0 = fmaf(e, w.x, a0);
        a1 = fmaf(e, w.y, a1);
    }
    #pragma unroll
    for (int off = 32; off > 0; off >>= 1) {
        a0 += __shfl_down(a0, off);
        a1 += __shfl_down(a1, off);
    }
    int samp = 0;
    if (l == 0) {
        float y0 = a0 + bf[0], y1 = a1 + bf[1];
        pred1[g * 2] = y0;
        pred1[g * 2 + 1] = y1;
        float m = fmaxf(y0, y1);
        float e0 = expf(y0 - m), e1 = expf(y1 - m), s = e0 + e1;
        float p0 = e0 / s, pp1 = e1 / s;
        float g0 = gumbel_from_bits(random_bits_partitionable(2 * g));
        float g1 = gumbel_from_bits(random_bits_partitionable(2 * g + 1));
        float l0 = logf(p0 + 1e-12f) + g0;
        float l1 = logf(pp1 + 1e-12f) + g1;
        samp = (l1 > l0) ? 1 : 0;
        ind[g] = (samp == targets[g]) ? 1.0f : 0.0f;
    }
    samp = __shfl(samp, 0);

    // ---- phase 2: Q-MLP (128->8 relu ->16 softmax) + feature_mask ----
    // lanes 0..39: p = l>>2 (cluster), s = l&3 (2 hidden units each)
    if (l < 40) {
        int p = l >> 2, s = l & 3;
        float ua = pb1[2 * s], ub = pb1[2 * s + 1];
        const float4* E4 = (const float4*)(E + (size_t)g * 1280 + p * DIM);
        #pragma unroll 4
        for (int k4 = 0; k4 < 32; k4++) {
            float4 e4 = E4[k4];
            float es[4] = {e4.x, e4.y, e4.z, e4.w};
            #pragma unroll
            for (int kk = 0; kk < 4; kk++) {
                int k = k4 * 4 + kk;
                ua = fmaf(es[kk], p1[k * PHID + 2 * s], ua);
                ub = fmaf(es[kk], p1[k * PHID + 2 * s + 1], ub);
            }
        }
        ua = fmaxf(ua, 0.f);
        ub = fmaxf(ub, 0.f);
        float v[NF];
        #pragma unroll
        for (int f = 0; f < NF; f++) {
            v[f] = pb2[f] * 0.25f;  // bias split across 4 lanes so reduce adds it once
            v[f] = fmaf(ua, p2[(2 * s) * NF + f], v[f]);
            v[f] = fmaf(ub, p2[(2 * s + 1) * NF + f], v[f]);
        }
        #pragma unroll
        for (int f = 0; f < NF; f++) {
            v[f] += __shfl_xor(v[f], 1);
            v[f] += __shfl_xor(v[f], 2);
        }
        float m = v[0];
        #pragma unroll
        for (int f = 1; f < NF; f++) m = fmaxf(m, v[f]);
        float ssum = 0.f, q[NF];
        #pragma unroll
        for (int f = 0; f < NF; f++) { q[f] = expf(v[f] - m); ssum += q[f]; }
        float inv = 1.0f / ssum;
        #pragma unroll
        for (int f = 0; f < NF; f++) q[f] *= inv;
        // store Q: lane s writes f = s*4 .. s*4+3 (float4)
        float* Qo = Q + ((size_t)g * NC + p) * NF;
        ((float4*)Qo)[s] = make_float4(q[s * 4], q[s * 4 + 1], q[s * 4 + 2], q[s * 4 + 3]);
        // feature_mask: fm_p = sum_f q[f] * corr[samp][f]
        float fmv = 0.f;
        #pragma unroll
        for (int f = 0; f < NF; f++) {
            float cv = __shfl(corr_lf, samp * NF + f);
            fmv = fmaf(q[f], cv, fmv);
        }
        if (s == 0) fmbuf[p] = fmv;
    }
    __syncthreads();

    // ---- phase 3: pred2 ----
    float b0 = 0.f, b1acc = 0.f;
    #pragma unroll
    for (int i = 0; i < 20; i++) {
        int idx = i * 64 + l;
        float e = Er[idx] * fmbuf[idx >> 7];
        float2 w = wf2[idx];
        b0 = fmaf(e, w.x, b0);
        b1acc = fmaf(e, w.y, b1acc);
    }
    #pragma unroll
    for (int off = 32; off > 0; off >>= 1) {
        b0 += __shfl_down(b0, off);
        b1acc += __shfl_down(b1acc, off);
    }
    if (l == 0) {
        pred2[g * 2] = b0 + bf[0];
        pred2[g * 2 + 1] = b1acc + bf[1];
    }
}

extern "C" void kernel_launch(void* const* d_in, const int* in_sizes, int n_in,
                              void* d_out, int out_size, void* d_ws, size_t ws_size,
                              hipStream_t stream) {
    const float* H       = (const float*)d_in[0];
    // d_in[1] = batch (implied by n/125, unused)
    const int*   targets = (const int*)d_in[2];
    const float* w1      = (const float*)d_in[3];
    const float* b1      = (const float*)d_in[4];
    const float* w2      = (const float*)d_in[5];
    const float* b2      = (const float*)d_in[6];
    const float* wf      = (const float*)d_in[7];
    const float* bf      = (const float*)d_in[8];
    const float* p1      = (const float*)d_in[9];
    const float* pb1     = (const float*)d_in[10];
    const float* p2      = (const float*)d_in[11];
    const float* pb2     = (const float*)d_in[12];
    const float* ci      = (const float*)d_in[13];
    const float* cr      = (const float*)d_in[14];

    float* out   = (float*)d_out;
    float* pred1 = out + OFF_PRED1;
    float* pred2 = out + OFF_PRED2;
    float* ind   = out + OFF_IND;
    float* S     = out + OFF_S;
    float* E     = out + OFF_E;
    float* Q     = out + OFF_Q;

    k_node_mlp<<<NN / 64, 64, 0, stream>>>(H, w1, b1, w2, b2, S);
    k_E<<<NG, 128, 0, stream>>>(H, S, E);
    k_tail<<<NG, 64, 0, stream>>>(E, wf, bf, targets, p1, pb1, p2, pb2, ci, cr,
                                  pred1, pred2, ind, Q);
}